// Round 8
// baseline (486.103 us; speedup 1.0000x reference)
//
#include <hip/hip_runtime.h>
#include <hip/hip_bf16.h>

#define NF 100000
#define TM 64
#define NB 1563   // ceil(NF/TM)

typedef __attribute__((ext_vector_type(8))) short bf16x8;
typedef __attribute__((ext_vector_type(4))) short bf16x4;
typedef __attribute__((ext_vector_type(4))) float f32x4;

__device__ __forceinline__ short bfs(float x) {
    union { __hip_bfloat16 h; short s; } u;
    u.h = __float2bfloat16(x);
    return u.s;
}

__device__ __forceinline__ float b2f(short s) {
    union { float f; unsigned u; } u;
    u.u = ((unsigned)(unsigned short)s) << 16;
    return u.f;
}

__device__ __forceinline__ bf16x8 cvt8(const float4 a, const float4 b) {
    bf16x8 r;
    r[0] = bfs(a.x); r[1] = bfs(a.y); r[2] = bfs(a.z); r[3] = bfs(a.w);
    r[4] = bfs(b.x); r[5] = bfs(b.y); r[6] = bfs(b.z); r[7] = bfs(b.w);
    return r;
}

__device__ __forceinline__ float mish_f(float v) {
    // mish(x) = x * (t^2+2t)/(t^2+2t+2), t=e^x; exact passthrough for v>20
    float t = __expf(v);
    float p = t * (t + 2.0f);
    float r = v * p * __builtin_amdgcn_rcpf(p + 2.0f);
    return (v > 20.0f) ? v : r;
}

// ---- fp32 -> bf16 pre-conversion ----
__global__ __launch_bounds__(256)
void cvt_emb(const float* __restrict__ in, __hip_bfloat16* __restrict__ out) {
    long e = ((long)blockIdx.x * 256 + threadIdx.x) * 8;
    const float4* s = (const float4*)(in + e);
    *(bf16x8*)(out + e) = cvt8(s[0], s[1]);
}

struct CvtW {
    const float* src[8];
    long pre[9];
};

__global__ __launch_bounds__(256)
void cvt_w(CvtW a, __hip_bfloat16* __restrict__ dst) {
    long e = ((long)blockIdx.x * 256 + threadIdx.x) * 8;
    if (e >= a.pre[8]) return;
    int k = 0;
    #pragma unroll
    for (int j = 0; j < 8; j++) if (e >= a.pre[j + 1]) k = j + 1;
    const float4* s = (const float4*)(a.src[k] + (e - a.pre[k]));
    *(bf16x8*)(dst + e) = cvt8(s[0], s[1]);
}

// ---- per-group fused kernel, NT fact-tiles per block with async gather staging ----
// Per tile: issue NEXT tile's idx+emb loads into regs (T14 issue-early), run
// GEMM1 -> mish -> GEMM2 -> residual-store, then commit staged regs to LDS
// (write-late). Gather latency exposed only on the block's first tile.
// Swapped MFMA (A=weight frag, B=fact frag): C/D col(lane&15)=fact row,
// row(kg*4+j)=4 consecutive output cols -> vector epilogues, float4 stores.
template<int D, int A, bool PRE, int MINW, int NT>
__global__ __launch_bounds__(256, MINW)
void msg_kernel(const void* __restrict__ embv,
                const int* __restrict__ idx,
                const void* __restrict__ wiv, const float* __restrict__ bi,
                const void* __restrict__ wov, const float* __restrict__ bo,
                float* __restrict__ out_msgs, float* __restrict__ out_idx)
{
    constexpr int DP = D + 8;             // row stride: conflict-free ds_read_b128 groups
    constexpr int CT = D / 64;
    constexpr int KS = D / 32;
    constexpr int RC = D / 8;
    constexpr int CH = (TM * RC) / 256;   // staged 16B chunks per thread
    __shared__ __hip_bfloat16 buf[TM][DP];

    const int g    = blockIdx.y;
    const int tid  = threadIdx.x;
    const int lane = tid & 63;
    const int w    = tid >> 6;
    const long gFA = (long)g * NF * A;
    const int tb0  = blockIdx.x * NT;

    const int ar = lane & 15;
    const int kg = lane >> 4;
    const int c0 = w * (D / 4);
    const long wbase = (long)g * D * D;

    int rr[CH], ii[CH];
    #pragma unroll
    for (int j = 0; j < CH; j++) {
        int c = tid + j * 256;
        rr[j] = c / RC;
        ii[j] = (c % RC) * 8;
    }

    bf16x8 sb[CH];                       // staged gather (PRE path)
    float4 sf[PRE ? 2 : 2 * CH];         // staged gather (f32 fallback)
    int sval = 0;

    auto stage = [&](int fb) {           // issue loads; DO NOT consume results here
        const int* idx_g = idx + gFA + (long)fb * TM * A;
        const int valid = min(TM, NF - fb * TM);
        #pragma unroll
        for (int j = 0; j < CH; j++) {
            if (rr[j] < valid) {
                int node = idx_g[rr[j] * A + (ii[j] >> 6)];
                if constexpr (PRE) {
                    sb[j] = *(const bf16x8*)((const __hip_bfloat16*)embv + (long)node * 64 + (ii[j] & 63));
                } else {
                    const float4* s = (const float4*)((const float*)embv + (long)node * 64 + (ii[j] & 63));
                    sf[2 * j] = s[0]; sf[2 * j + 1] = s[1];
                }
            } else {
                if constexpr (PRE) sb[j] = (bf16x8)0;
                else { sf[2 * j] = float4{0, 0, 0, 0}; sf[2 * j + 1] = float4{0, 0, 0, 0}; }
            }
        }
        sval = (tid < valid * A) ? idx_g[tid] : 0;
    };

    auto commit = [&]() {                // consume staged regs -> LDS
        #pragma unroll
        for (int j = 0; j < CH; j++) {
            if constexpr (PRE) *(bf16x8*)(&buf[rr[j]][ii[j]]) = sb[j];
            else               *(bf16x8*)(&buf[rr[j]][ii[j]]) = cvt8(sf[2 * j], sf[2 * j + 1]);
        }
    };

    stage(tb0);
    commit();
    __syncthreads();

    #pragma unroll 1
    for (int t = 0; t < NT; t++) {
        const int fb = tb0 + t;
        if (fb >= NB) break;
        const int valid = min(TM, NF - fb * TM);
        const int svcur = sval;
        const bool more = (t + 1 < NT) && (fb + 1 < NB);
        if (more) stage(fb + 1);         // loads retire under the two GEMMs below

        f32x4 acc[4][CT];
        #pragma unroll
        for (int rt = 0; rt < 4; rt++)
            #pragma unroll
            for (int ct = 0; ct < CT; ct++) acc[rt][ct] = (f32x4)0.0f;

        // ---- GEMM1: Wi x X^T ----
        #pragma unroll
        for (int ks = 0; ks < KS; ks++) {
            const int kk = ks * 32;
            bf16x8 xb[4];
            #pragma unroll
            for (int rt = 0; rt < 4; rt++) xb[rt] = *(const bf16x8*)(&buf[rt * 16 + ar][kk + kg * 8]);
            #pragma unroll
            for (int ct = 0; ct < CT; ct++) {
                bf16x8 wf;
                const long wofs = wbase + (long)(c0 + ct * 16 + ar) * D + kk + kg * 8;
                if constexpr (PRE) wf = *(const bf16x8*)((const __hip_bfloat16*)wiv + wofs);
                else { const float4* bp = (const float4*)((const float*)wiv + wofs); wf = cvt8(bp[0], bp[1]); }
                #pragma unroll
                for (int rt = 0; rt < 4; rt++)
                    acc[rt][ct] = __builtin_amdgcn_mfma_f32_16x16x32_bf16(wf, xb[rt], acc[rt][ct], 0, 0, 0);
            }
        }

        // ---- snapshot residual X values (per-lane 4 cols x 4 row-tiles) ----
        bf16x4 res[4][CT];
        #pragma unroll
        for (int ct = 0; ct < CT; ct++) {
            const int cb = c0 + ct * 16 + kg * 4;
            #pragma unroll
            for (int rt = 0; rt < 4; rt++)
                res[rt][ct] = *(const bf16x4*)(&buf[rt * 16 + ar][cb]);
        }

        // idx output for this tile (value was loaded at stage time)
        if (tid < valid * A)
            out_idx[gFA + (long)fb * TM * A + tid] = (float)svcur;

        __syncthreads();   // all X reads complete before H overwrites buf

        // ---- epilogue 1: bias + mish -> buf (H) ----
        #pragma unroll
        for (int ct = 0; ct < CT; ct++) {
            const int cb = c0 + ct * 16 + kg * 4;
            const float4 bi4 = *(const float4*)(bi + g * D + cb);
            #pragma unroll
            for (int rt = 0; rt < 4; rt++) {
                bf16x4 hv;
                hv[0] = bfs(mish_f(acc[rt][ct][0] + bi4.x));
                hv[1] = bfs(mish_f(acc[rt][ct][1] + bi4.y));
                hv[2] = bfs(mish_f(acc[rt][ct][2] + bi4.z));
                hv[3] = bfs(mish_f(acc[rt][ct][3] + bi4.w));
                *(bf16x4*)(&buf[rt * 16 + ar][cb]) = hv;
            }
        }
        __syncthreads();

        // ---- GEMM2: Wo x H^T ----
        #pragma unroll
        for (int rt = 0; rt < 4; rt++)
            #pragma unroll
            for (int ct = 0; ct < CT; ct++) acc[rt][ct] = (f32x4)0.0f;

        #pragma unroll
        for (int ks = 0; ks < KS; ks++) {
            const int kk = ks * 32;
            bf16x8 hb[4];
            #pragma unroll
            for (int rt = 0; rt < 4; rt++) hb[rt] = *(const bf16x8*)(&buf[rt * 16 + ar][kk + kg * 8]);
            #pragma unroll
            for (int ct = 0; ct < CT; ct++) {
                bf16x8 wf;
                const long wofs = wbase + (long)(c0 + ct * 16 + ar) * D + kk + kg * 8;
                if constexpr (PRE) wf = *(const bf16x8*)((const __hip_bfloat16*)wov + wofs);
                else { const float4* bp = (const float4*)((const float*)wov + wofs); wf = cvt8(bp[0], bp[1]); }
                #pragma unroll
                for (int rt = 0; rt < 4; rt++)
                    acc[rt][ct] = __builtin_amdgcn_mfma_f32_16x16x32_bf16(wf, hb[rt], acc[rt][ct], 0, 0, 0);
            }
        }

        // ---- epilogue 2: bias + residual(regs), float4 stores ----
        {
            float* ob = out_msgs + (gFA + (long)fb * TM * A) * 64;
            #pragma unroll
            for (int ct = 0; ct < CT; ct++) {
                const int cb = c0 + ct * 16 + kg * 4;
                const float4 bo4 = *(const float4*)(bo + g * D + cb);
                #pragma unroll
                for (int rt = 0; rt < 4; rt++) {
                    const int r = rt * 16 + ar;
                    float4 o;
                    o.x = acc[rt][ct][0] + bo4.x + b2f(res[rt][ct][0]);
                    o.y = acc[rt][ct][1] + bo4.y + b2f(res[rt][ct][1]);
                    o.z = acc[rt][ct][2] + bo4.z + b2f(res[rt][ct][2]);
                    o.w = acc[rt][ct][3] + bo4.w + b2f(res[rt][ct][3]);
                    if (r < valid) *(float4*)(ob + (long)r * D + cb) = o;
                }
            }
        }

        if (more) {
            __syncthreads();   // all H reads done before X(t+1) overwrites buf
            commit();          // waits on staged loads (long since retired)
            __syncthreads();
        }
    }
}

extern "C" void kernel_launch(void* const* d_in, const int* in_sizes, int n_in,
                              void* d_out, int out_size, void* d_ws, size_t ws_size,
                              hipStream_t stream) {
    const float* emb_f = (const float*)d_in[0];
    const int Gs[4] = {2, 3, 2, 1};
    const int Ds[4] = {64, 128, 192, 256};

    const int*   idx_a[4];
    const float *wi_f[4], *bi_f[4], *wo_f[4], *bo_f[4];
    for (int k = 0; k < 4; k++) {
        idx_a[k] = (const int*)d_in[1 + 5 * k];
        wi_f[k]  = (const float*)d_in[2 + 5 * k];
        bi_f[k]  = (const float*)d_in[3 + 5 * k];
        wo_f[k]  = (const float*)d_in[4 + 5 * k];
        bo_f[k]  = (const float*)d_in[5 + 5 * k];
    }

    float* out = (float*)d_out;
    const long MSG_ELEMS = 115200000L;
    const long rowOff[4] = {0, 200000, 800000, 1400000};
    float* om[4]; float* oi[4];
    for (int k = 0; k < 4; k++) {
        om[k] = out + rowOff[k] * 64;
        oi[k] = out + MSG_ELEMS + rowOff[k];
    }

    const long EMB_ELEMS = 6400000L;
    long wPre[9]; wPre[0] = 0;
    for (int k = 0; k < 4; k++) {
        long we = (long)Gs[k] * Ds[k] * Ds[k];
        wPre[2 * k + 1] = wPre[2 * k] + we;
        wPre[2 * k + 2] = wPre[2 * k + 1] + we;
    }
    const long NEED = (EMB_ELEMS + wPre[8]) * 2;

    // grid.x per NT: NT=4 -> 391, NT=2 -> 782, NT=3 -> 521
    if (ws_size >= (size_t)NEED) {
        __hip_bfloat16* emb_b = (__hip_bfloat16*)d_ws;
        __hip_bfloat16* w_b   = emb_b + EMB_ELEMS;

        cvt_emb<<<dim3(EMB_ELEMS / 8 / 256), dim3(256), 0, stream>>>(emb_f, emb_b);
        CvtW cw;
        for (int k = 0; k < 4; k++) { cw.src[2 * k] = wi_f[k]; cw.src[2 * k + 1] = wo_f[k]; }
        for (int j = 0; j < 9; j++) cw.pre[j] = wPre[j];
        cvt_w<<<dim3((wPre[8] / 8 + 255) / 256), dim3(256), 0, stream>>>(cw, w_b);

        const __hip_bfloat16 *wi_b[4], *wo_b[4];
        for (int k = 0; k < 4; k++) { wi_b[k] = w_b + wPre[2 * k]; wo_b[k] = w_b + wPre[2 * k + 1]; }

        msg_kernel<64, 1, true, 4, 4><<<dim3(391, 2), 256, 0, stream>>>(
            emb_b, idx_a[0], wi_b[0], bi_f[0], wo_b[0], bo_f[0], om[0], oi[0]);
        msg_kernel<128, 2, true, 4, 2><<<dim3(782, 3), 256, 0, stream>>>(
            emb_b, idx_a[1], wi_b[1], bi_f[1], wo_b[1], bo_f[1], om[1], oi[1]);
        msg_kernel<192, 3, true, 3, 2><<<dim3(782, 2), 256, 0, stream>>>(
            emb_b, idx_a[2], wi_b[2], bi_f[2], wo_b[2], bo_f[2], om[2], oi[2]);
        msg_kernel<256, 4, true, 2, 3><<<dim3(521, 1), 256, 0, stream>>>(
            emb_b, idx_a[3], wi_b[3], bi_f[3], wo_b[3], bo_f[3], om[3], oi[3]);
    } else {
        msg_kernel<64, 1, false, 4, 4><<<dim3(391, 2), 256, 0, stream>>>(
            emb_f, idx_a[0], wi_f[0], bi_f[0], wo_f[0], bo_f[0], om[0], oi[0]);
        msg_kernel<128, 2, false, 4, 2><<<dim3(782, 3), 256, 0, stream>>>(
            emb_f, idx_a[1], wi_f[1], bi_f[1], wo_f[1], bo_f[1], om[1], oi[1]);
        msg_kernel<192, 3, false, 3, 2><<<dim3(782, 2), 256, 0, stream>>>(
            emb_f, idx_a[2], wi_f[2], bi_f[2], wo_f[2], bo_f[2], om[2], oi[2]);
        msg_kernel<256, 4, false, 2, 3><<<dim3(521, 1), 256, 0, stream>>>(
            emb_f, idx_a[3], wi_f[3], bi_f[3], wo_f[3], bo_f[3], om[3], oi[3]);
    }
}

// Round 9
// 380.684 us; speedup vs baseline: 1.2769x; 1.2769x over previous
//
#include <hip/hip_runtime.h>
#include <hip/hip_bf16.h>

#define NF 100000
#define NFP 100032   // NB*TM, padded rows for X_packed
#define TM 64
#define NB 1563      // ceil(NF/TM)

typedef __attribute__((ext_vector_type(8))) short bf16x8;
typedef __attribute__((ext_vector_type(4))) short bf16x4;
typedef __attribute__((ext_vector_type(4))) float f32x4;

__device__ __forceinline__ short bfs(float x) {
    union { __hip_bfloat16 h; short s; } u;
    u.h = __float2bfloat16(x);
    return u.s;
}

__device__ __forceinline__ float b2f(short s) {
    union { float f; unsigned u; } u;
    u.u = ((unsigned)(unsigned short)s) << 16;
    return u.f;
}

__device__ __forceinline__ bf16x8 cvt8(const float4 a, const float4 b) {
    bf16x8 r;
    r[0] = bfs(a.x); r[1] = bfs(a.y); r[2] = bfs(a.z); r[3] = bfs(a.w);
    r[4] = bfs(b.x); r[5] = bfs(b.y); r[6] = bfs(b.z); r[7] = bfs(b.w);
    return r;
}

__device__ __forceinline__ float mish_f(float v) {
    float t = __expf(v);
    float p = t * (t + 2.0f);
    float r = v * p * __builtin_amdgcn_rcpf(p + 2.0f);
    return (v > 20.0f) ? v : r;
}

// ---- fp32 -> bf16 pre-conversion ----
__global__ __launch_bounds__(256)
void cvt_emb(const float* __restrict__ in, __hip_bfloat16* __restrict__ out) {
    long e = ((long)blockIdx.x * 256 + threadIdx.x) * 8;
    const float4* s = (const float4*)(in + e);
    *(bf16x8*)(out + e) = cvt8(s[0], s[1]);
}

struct CvtW {
    const float* src[8];
    long pre[9];
};

__global__ __launch_bounds__(256)
void cvt_w(CvtW a, __hip_bfloat16* __restrict__ dst) {
    long e = ((long)blockIdx.x * 256 + threadIdx.x) * 8;
    if (e >= a.pre[8]) return;
    int k = 0;
    #pragma unroll
    for (int j = 0; j < 8; j++) if (e >= a.pre[j + 1]) k = j + 1;
    const float4* s = (const float4*)(a.src[k] + (e - a.pre[k]));
    *(bf16x8*)(dst + e) = cvt8(s[0], s[1]);
}

// ---- Kernel A: streaming gather into packed, pre-swizzled X (+idx out) ----
// X layout: [G][NFP][D] bf16, with per-row swizzle byte ^= (f&7)<<4 so kernel B's
// stride-2D ds_read_b128 is bank-conflict-free while the LDS copy stays linear.
template<int D, int A>
__global__ __launch_bounds__(256)
void gather_pack(const __hip_bfloat16* __restrict__ emb,
                 const int* __restrict__ idx,
                 char* __restrict__ Xp,
                 float* __restrict__ out_idx,
                 int nchunks)
{
    constexpr int CPF = D / 8;                 // 16B chunks per fact
    int t = blockIdx.x * 256 + threadIdx.x;
    if (t >= nchunks) return;
    int g = t / (NF * CPF);
    int r = t - g * (NF * CPF);
    int f = r / CPF;
    int c16 = r - f * CPF;
    int row = (g * NF + f) * A + (c16 >> 3);   // flat idx-row
    int node = idx[row];
    bf16x8 v = *(const bf16x8*)(emb + (long)node * 64 + (c16 & 7) * 8);
    long db = ((long)g * NFP + f) * (2 * D) + c16 * 16;
    db ^= (f & 7) << 4;
    *(bf16x8*)(Xp + db) = v;
    if ((c16 & 7) == 0) out_idx[row] = (float)node;
}

// ---- Kernel B: pure GEMM pipeline over packed X ----
// R7 structure: 4 waves, each all 64 facts x D/4 cols (RT=4, CT=D/64); swapped
// MFMA (A=weight frag, B=fact frag) -> 4 consecutive out cols/lane; single LDS
// buffer (X then H) with register residual snapshot; float4 stores.
template<int D, int A, int MINW>
__global__ __launch_bounds__(256, MINW)
void gemm_kernel(const char* __restrict__ Xp,
                 const __hip_bfloat16* __restrict__ wi, const float* __restrict__ bi,
                 const __hip_bfloat16* __restrict__ wo, const float* __restrict__ bo,
                 float* __restrict__ out_msgs)
{
    constexpr int CT = D / 64;
    constexpr int KS = D / 32;
    constexpr int CHS = (TM * 2 * D) / (16 * 256);   // 16B chunks per thread
    __shared__ __align__(16) char buf[TM * 2 * D];   // linear, swizzled content

    const int g    = blockIdx.y;
    const int f0   = blockIdx.x * TM;
    const int tid  = threadIdx.x;
    const int lane = tid & 63;
    const int w    = tid >> 6;
    const int valid = min(TM, NF - f0);

    // ---- stage X tile: linear contiguous copy (swizzle already baked in) ----
    {
        const char* src = Xp + ((long)g * NFP + f0) * (2 * D);
        #pragma unroll
        for (int j = 0; j < CHS; j++) {
            int o = (tid + j * 256) * 16;
            *(bf16x8*)(buf + o) = *(const bf16x8*)(src + o);
        }
    }
    __syncthreads();

    const int ar = lane & 15;
    const int kg = lane >> 4;
    const int c0 = w * (D / 4);
    const long wbase = (long)g * D * D;

    f32x4 acc[4][CT];
    #pragma unroll
    for (int rt = 0; rt < 4; rt++)
        #pragma unroll
        for (int ct = 0; ct < CT; ct++) acc[rt][ct] = (f32x4)0.0f;

    // ---- GEMM1: Wi x X^T ----
    #pragma unroll
    for (int ks = 0; ks < KS; ks++) {
        const int kk = ks * 32;
        bf16x8 xb[4];
        #pragma unroll
        for (int rt = 0; rt < 4; rt++) {
            int o = ((rt * 16 + ar) * (2 * D) + (kk + kg * 8) * 2) ^ ((ar & 7) << 4);
            xb[rt] = *(const bf16x8*)(buf + o);
        }
        #pragma unroll
        for (int ct = 0; ct < CT; ct++) {
            bf16x8 wf = *(const bf16x8*)(wi + wbase + (long)(c0 + ct * 16 + ar) * D + kk + kg * 8);
            #pragma unroll
            for (int rt = 0; rt < 4; rt++)
                acc[rt][ct] = __builtin_amdgcn_mfma_f32_16x16x32_bf16(wf, xb[rt], acc[rt][ct], 0, 0, 0);
        }
    }

    // ---- snapshot residual X values to regs ----
    bf16x4 res[4][CT];
    #pragma unroll
    for (int ct = 0; ct < CT; ct++) {
        const int cb = c0 + ct * 16 + kg * 4;
        #pragma unroll
        for (int rt = 0; rt < 4; rt++) {
            int o = ((rt * 16 + ar) * (2 * D) + cb * 2) ^ ((ar & 7) << 4);
            res[rt][ct] = *(const bf16x4*)(buf + o);
        }
    }
    __syncthreads();   // all X reads done before H overwrites buf

    // ---- epilogue 1: bias + mish -> buf (H, same swizzle) ----
    #pragma unroll
    for (int ct = 0; ct < CT; ct++) {
        const int cb = c0 + ct * 16 + kg * 4;
        const float4 bi4 = *(const float4*)(bi + g * D + cb);
        #pragma unroll
        for (int rt = 0; rt < 4; rt++) {
            bf16x4 hv;
            hv[0] = bfs(mish_f(acc[rt][ct][0] + bi4.x));
            hv[1] = bfs(mish_f(acc[rt][ct][1] + bi4.y));
            hv[2] = bfs(mish_f(acc[rt][ct][2] + bi4.z));
            hv[3] = bfs(mish_f(acc[rt][ct][3] + bi4.w));
            int o = ((rt * 16 + ar) * (2 * D) + cb * 2) ^ ((ar & 7) << 4);
            *(bf16x4*)(buf + o) = hv;
        }
    }
    __syncthreads();

    // ---- GEMM2: Wo x H^T ----
    #pragma unroll
    for (int rt = 0; rt < 4; rt++)
        #pragma unroll
        for (int ct = 0; ct < CT; ct++) acc[rt][ct] = (f32x4)0.0f;

    #pragma unroll
    for (int ks = 0; ks < KS; ks++) {
        const int kk = ks * 32;
        bf16x8 hb[4];
        #pragma unroll
        for (int rt = 0; rt < 4; rt++) {
            int o = ((rt * 16 + ar) * (2 * D) + (kk + kg * 8) * 2) ^ ((ar & 7) << 4);
            hb[rt] = *(const bf16x8*)(buf + o);
        }
        #pragma unroll
        for (int ct = 0; ct < CT; ct++) {
            bf16x8 wf = *(const bf16x8*)(wo + wbase + (long)(c0 + ct * 16 + ar) * D + kk + kg * 8);
            #pragma unroll
            for (int rt = 0; rt < 4; rt++)
                acc[rt][ct] = __builtin_amdgcn_mfma_f32_16x16x32_bf16(wf, hb[rt], acc[rt][ct], 0, 0, 0);
        }
    }

    // ---- epilogue 2: bias + residual(regs), float4 stores ----
    {
        float* ob = out_msgs + ((long)g * NF + f0) * D;
        #pragma unroll
        for (int ct = 0; ct < CT; ct++) {
            const int cb = c0 + ct * 16 + kg * 4;
            const float4 bo4 = *(const float4*)(bo + g * D + cb);
            #pragma unroll
            for (int rt = 0; rt < 4; rt++) {
                const int r = rt * 16 + ar;
                float4 o;
                o.x = acc[rt][ct][0] + bo4.x + b2f(res[rt][ct][0]);
                o.y = acc[rt][ct][1] + bo4.y + b2f(res[rt][ct][1]);
                o.z = acc[rt][ct][2] + bo4.z + b2f(res[rt][ct][2]);
                o.w = acc[rt][ct][3] + bo4.w + b2f(res[rt][ct][3]);
                if (r < valid) *(float4*)(ob + (long)r * D + cb) = o;
            }
        }
    }
}

// ---- R7 fused kernel (fallback when ws too small for the split path) ----
template<int D, int A, bool PRE, int MINW>
__global__ __launch_bounds__(256, MINW)
void msg_kernel(const void* __restrict__ embv,
                const int* __restrict__ idx,
                const void* __restrict__ wiv, const float* __restrict__ bi,
                const void* __restrict__ wov, const float* __restrict__ bo,
                float* __restrict__ out_msgs, float* __restrict__ out_idx)
{
    constexpr int DP = D + 8;
    constexpr int CT = D / 64;
    constexpr int KS = D / 32;
    constexpr int RC = D / 8;
    __shared__ __hip_bfloat16 buf[TM][DP];

    const int g    = blockIdx.y;
    const int f0   = blockIdx.x * TM;
    const int tid  = threadIdx.x;
    const int lane = tid & 63;
    const int w    = tid >> 6;
    const long gFA = (long)g * NF * A;
    const int valid = min(TM, NF - f0);

    {
        const int* idx_g = idx + gFA + (long)f0 * A;
        #pragma unroll
        for (int c = tid; c < TM * RC; c += 256) {
            int r = c / RC;
            int i = (c - r * RC) * 8;
            bf16x8 v = (bf16x8)0;
            if (r < valid) {
                int node = idx_g[r * A + (i >> 6)];
                if constexpr (PRE) {
                    v = *(const bf16x8*)((const __hip_bfloat16*)embv + (long)node * 64 + (i & 63));
                } else {
                    const float4* s = (const float4*)((const float*)embv + (long)node * 64 + (i & 63));
                    v = cvt8(s[0], s[1]);
                }
            }
            *(bf16x8*)(&buf[r][i]) = v;
        }
        if (tid < valid * A) out_idx[gFA + (long)f0 * A + tid] = (float)idx_g[tid];
    }
    __syncthreads();

    const int ar = lane & 15;
    const int kg = lane >> 4;
    const int c0 = w * (D / 4);
    const long wbase = (long)g * D * D;

    f32x4 acc[4][CT];
    #pragma unroll
    for (int rt = 0; rt < 4; rt++)
        #pragma unroll
        for (int ct = 0; ct < CT; ct++) acc[rt][ct] = (f32x4)0.0f;

    #pragma unroll
    for (int ks = 0; ks < KS; ks++) {
        const int kk = ks * 32;
        bf16x8 xb[4];
        #pragma unroll
        for (int rt = 0; rt < 4; rt++) xb[rt] = *(const bf16x8*)(&buf[rt * 16 + ar][kk + kg * 8]);
        #pragma unroll
        for (int ct = 0; ct < CT; ct++) {
            bf16x8 wf;
            const long wofs = wbase + (long)(c0 + ct * 16 + ar) * D + kk + kg * 8;
            if constexpr (PRE) wf = *(const bf16x8*)((const __hip_bfloat16*)wiv + wofs);
            else { const float4* bp = (const float4*)((const float*)wiv + wofs); wf = cvt8(bp[0], bp[1]); }
            #pragma unroll
            for (int rt = 0; rt < 4; rt++)
                acc[rt][ct] = __builtin_amdgcn_mfma_f32_16x16x32_bf16(wf, xb[rt], acc[rt][ct], 0, 0, 0);
        }
    }

    bf16x4 res[4][CT];
    #pragma unroll
    for (int ct = 0; ct < CT; ct++) {
        const int cb = c0 + ct * 16 + kg * 4;
        #pragma unroll
        for (int rt = 0; rt < 4; rt++)
            res[rt][ct] = *(const bf16x4*)(&buf[rt * 16 + ar][cb]);
    }
    __syncthreads();

    #pragma unroll
    for (int ct = 0; ct < CT; ct++) {
        const int cb = c0 + ct * 16 + kg * 4;
        const float4 bi4 = *(const float4*)(bi + g * D + cb);
        #pragma unroll
        for (int rt = 0; rt < 4; rt++) {
            bf16x4 hv;
            hv[0] = bfs(mish_f(acc[rt][ct][0] + bi4.x));
            hv[1] = bfs(mish_f(acc[rt][ct][1] + bi4.y));
            hv[2] = bfs(mish_f(acc[rt][ct][2] + bi4.z));
            hv[3] = bfs(mish_f(acc[rt][ct][3] + bi4.w));
            *(bf16x4*)(&buf[rt * 16 + ar][cb]) = hv;
        }
    }
    __syncthreads();

    #pragma unroll
    for (int rt = 0; rt < 4; rt++)
        #pragma unroll
        for (int ct = 0; ct < CT; ct++) acc[rt][ct] = (f32x4)0.0f;

    #pragma unroll
    for (int ks = 0; ks < KS; ks++) {
        const int kk = ks * 32;
        bf16x8 hb[4];
        #pragma unroll
        for (int rt = 0; rt < 4; rt++) hb[rt] = *(const bf16x8*)(&buf[rt * 16 + ar][kk + kg * 8]);
        #pragma unroll
        for (int ct = 0; ct < CT; ct++) {
            bf16x8 wf;
            const long wofs = wbase + (long)(c0 + ct * 16 + ar) * D + kk + kg * 8;
            if constexpr (PRE) wf = *(const bf16x8*)((const __hip_bfloat16*)wov + wofs);
            else { const float4* bp = (const float4*)((const float*)wov + wofs); wf = cvt8(bp[0], bp[1]); }
            #pragma unroll
            for (int rt = 0; rt < 4; rt++)
                acc[rt][ct] = __builtin_amdgcn_mfma_f32_16x16x32_bf16(wf, hb[rt], acc[rt][ct], 0, 0, 0);
        }
    }

    {
        float* ob = out_msgs + (gFA + (long)f0 * A) * 64;
        #pragma unroll
        for (int ct = 0; ct < CT; ct++) {
            const int cb = c0 + ct * 16 + kg * 4;
            const float4 bo4 = *(const float4*)(bo + g * D + cb);
            #pragma unroll
            for (int rt = 0; rt < 4; rt++) {
                const int r = rt * 16 + ar;
                float4 o;
                o.x = acc[rt][ct][0] + bo4.x + b2f(res[rt][ct][0]);
                o.y = acc[rt][ct][1] + bo4.y + b2f(res[rt][ct][1]);
                o.z = acc[rt][ct][2] + bo4.z + b2f(res[rt][ct][2]);
                o.w = acc[rt][ct][3] + bo4.w + b2f(res[rt][ct][3]);
                if (r < valid) *(float4*)(ob + (long)r * D + cb) = o;
            }
        }
    }
}

extern "C" void kernel_launch(void* const* d_in, const int* in_sizes, int n_in,
                              void* d_out, int out_size, void* d_ws, size_t ws_size,
                              hipStream_t stream) {
    const float* emb_f = (const float*)d_in[0];
    const int Gs[4] = {2, 3, 2, 1};
    const int Ds[4] = {64, 128, 192, 256};

    const int*   idx_a[4];
    const float *wi_f[4], *bi_f[4], *wo_f[4], *bo_f[4];
    for (int k = 0; k < 4; k++) {
        idx_a[k] = (const int*)d_in[1 + 5 * k];
        wi_f[k]  = (const float*)d_in[2 + 5 * k];
        bi_f[k]  = (const float*)d_in[3 + 5 * k];
        wo_f[k]  = (const float*)d_in[4 + 5 * k];
        bo_f[k]  = (const float*)d_in[5 + 5 * k];
    }

    float* out = (float*)d_out;
    const long MSG_ELEMS = 115200000L;
    const long rowOff[4] = {0, 200000, 800000, 1400000};
    float* om[4]; float* oi[4];
    for (int k = 0; k < 4; k++) {
        om[k] = out + rowOff[k] * 64;
        oi[k] = out + MSG_ELEMS + rowOff[k];
    }

    const long EMB_ELEMS = 6400000L;
    long wPre[9]; wPre[0] = 0;
    for (int k = 0; k < 4; k++) {
        long we = (long)Gs[k] * Ds[k] * Ds[k];
        wPre[2 * k + 1] = wPre[2 * k] + we;
        wPre[2 * k + 2] = wPre[2 * k + 1] + we;
    }
    const long NEED1  = (EMB_ELEMS + wPre[8]) * 2;
    const long XBYTES = 3L * NFP * 128 * 2;          // max group (a=2): 76.8 MB
    const long NEED2  = NEED1 + XBYTES;

    if (ws_size >= (size_t)NEED1) {
        __hip_bfloat16* emb_b = (__hip_bfloat16*)d_ws;
        __hip_bfloat16* w_b   = emb_b + EMB_ELEMS;

        cvt_emb<<<dim3(EMB_ELEMS / 8 / 256), dim3(256), 0, stream>>>(emb_f, emb_b);
        CvtW cw;
        for (int k = 0; k < 4; k++) { cw.src[2 * k] = wi_f[k]; cw.src[2 * k + 1] = wo_f[k]; }
        for (int j = 0; j < 9; j++) cw.pre[j] = wPre[j];
        cvt_w<<<dim3((wPre[8] / 8 + 255) / 256), dim3(256), 0, stream>>>(cw, w_b);

        const __hip_bfloat16 *wi_b[4], *wo_b[4];
        for (int k = 0; k < 4; k++) { wi_b[k] = w_b + wPre[2 * k]; wo_b[k] = w_b + wPre[2 * k + 1]; }

        if (ws_size >= (size_t)NEED2) {
            // ---- split path: gather_pack -> gemm per group, X buffer reused ----
            char* Xp = (char*)(w_b + wPre[8]);

            {   // a=1, D=64, G=2
                int nch = 2 * NF * 8;
                gather_pack<64, 1><<<dim3((nch + 255) / 256), 256, 0, stream>>>(emb_b, idx_a[0], Xp, oi[0], nch);
                gemm_kernel<64, 1, 4><<<dim3(NB, 2), 256, 0, stream>>>(Xp, wi_b[0], bi_f[0], wo_b[0], bo_f[0], om[0]);
            }
            {   // a=2, D=128, G=3
                int nch = 3 * NF * 16;
                gather_pack<128, 2><<<dim3((nch + 255) / 256), 256, 0, stream>>>(emb_b, idx_a[1], Xp, oi[1], nch);
                gemm_kernel<128, 2, 4><<<dim3(NB, 3), 256, 0, stream>>>(Xp, wi_b[1], bi_f[1], wo_b[1], bo_f[1], om[1]);
            }
            {   // a=3, D=192, G=2
                int nch = 2 * NF * 24;
                gather_pack<192, 3><<<dim3((nch + 255) / 256), 256, 0, stream>>>(emb_b, idx_a[2], Xp, oi[2], nch);
                gemm_kernel<192, 3, 4><<<dim3(NB, 2), 256, 0, stream>>>(Xp, wi_b[2], bi_f[2], wo_b[2], bo_f[2], om[2]);
            }
            {   // a=4, D=256, G=1
                int nch = 1 * NF * 32;
                gather_pack<256, 4><<<dim3((nch + 255) / 256), 256, 0, stream>>>(emb_b, idx_a[3], Xp, oi[3], nch);
                gemm_kernel<256, 4, 3><<<dim3(NB, 1), 256, 0, stream>>>(Xp, wi_b[3], bi_f[3], wo_b[3], bo_f[3], om[3]);
            }
        } else {
            msg_kernel<64, 1, true, 4><<<dim3(NB, 2), 256, 0, stream>>>(
                emb_b, idx_a[0], wi_b[0], bi_f[0], wo_b[0], bo_f[0], om[0], oi[0]);
            msg_kernel<128, 2, true, 4><<<dim3(NB, 3), 256, 0, stream>>>(
                emb_b, idx_a[1], wi_b[1], bi_f[1], wo_b[1], bo_f[1], om[1], oi[1]);
            msg_kernel<192, 3, true, 4><<<dim3(NB, 2), 256, 0, stream>>>(
                emb_b, idx_a[2], wi_b[2], bi_f[2], wo_b[2], bo_f[2], om[2], oi[2]);
            msg_kernel<256, 4, true, 3><<<dim3(NB, 1), 256, 0, stream>>>(
                emb_b, idx_a[3], wi_b[3], bi_f[3], wo_b[3], bo_f[3], om[3], oi[3]);
        }
    } else {
        msg_kernel<64, 1, false, 4><<<dim3(NB, 2), 256, 0, stream>>>(
            emb_f, idx_a[0], wi_f[0], bi_f[0], wo_f[0], bo_f[0], om[0], oi[0]);
        msg_kernel<128, 2, false, 4><<<dim3(NB, 3), 256, 0, stream>>>(
            emb_f, idx_a[1], wi_f[1], bi_f[1], wo_f[1], bo_f[1], om[1], oi[1]);
        msg_kernel<192, 3, false, 4><<<dim3(NB, 2), 256, 0, stream>>>(
            emb_f, idx_a[2], wi_f[2], bi_f[2], wo_f[2], bo_f[2], om[2], oi[2]);
        msg_kernel<256, 4, false, 3><<<dim3(NB, 1), 256, 0, stream>>>(
            emb_f, idx_a[3], wi_f[3], bi_f[3], wo_f[3], bo_f[3], om[3], oi[3]);
    }
}